// Round 1
// baseline (785.837 us; speedup 1.0000x reference)
//
#include <hip/hip_runtime.h>

// VQ codebook nearest-neighbor:
//   x_in:  [B=16, EMB=64, CODES=16384] f32
//   E:     [NT=1024, EMB=64] f32
//   out0:  x_out [B, EMB, CODES] f32  = E[argmin][e]
//   out1:  indices [B, CODES, 1] written as f32 values
//
// argmin_k ||x - E_k||^2  ==  argmax_k ( x . E_k - 0.5*||E_k||^2 )

#define BB 16
#define EMB 64
#define CODES 16384
#define NT 1024

__global__ __launch_bounds__(256) void vq_kernel(
    const float* __restrict__ x, const float* __restrict__ E,
    float* __restrict__ xout, float* __restrict__ iout) {
  __shared__ float hs[NT];  // -0.5 * ||E_k||^2
  const int tid = threadIdx.x;

  // Per-block precompute of -0.5*||E_k||^2 (adds ~0.4% FLOPs; E is L2-hot)
  #pragma unroll
  for (int r = 0; r < 4; ++r) {
    const int k = r * 256 + tid;
    const float4* __restrict__ Ek = (const float4*)(E + k * EMB);
    float s = 0.f;
    #pragma unroll
    for (int i = 0; i < 16; ++i) {
      float4 v = Ek[i];
      s += v.x * v.x + v.y * v.y + v.z * v.z + v.w * v.w;
    }
    hs[k] = -0.5f * s;
  }
  __syncthreads();

  const int b = blockIdx.y;
  const int c = blockIdx.x * 256 + tid;

  // Load this code's 64-dim query into registers (coalesced across lanes:
  // fixed e => consecutive c are consecutive addresses)
  const float* __restrict__ xp = x + (size_t)b * (EMB * (size_t)CODES) + c;
  float xr[EMB];
  #pragma unroll
  for (int e = 0; e < EMB; ++e) xr[e] = xp[(size_t)e * CODES];

  float best = -3.4e38f;
  int bidx = 0;

  // Hot loop: E row addresses are wave-uniform (depend only on k) so the
  // compiler emits s_load_dwordx4 -> SGPR broadcast; VALU does pure v_fmac
  // with one SGPR operand. 4 accumulators break the FMA dep chain.
  for (int k = 0; k < NT; ++k) {
    const float4* __restrict__ Ek = (const float4*)(E + k * EMB);
    float s0 = hs[k], s1 = 0.f, s2 = 0.f, s3 = 0.f;
    #pragma unroll
    for (int i = 0; i < 16; i += 4) {
      float4 v0 = Ek[i + 0];
      float4 v1 = Ek[i + 1];
      float4 v2 = Ek[i + 2];
      float4 v3 = Ek[i + 3];
      s0 = fmaf(xr[4 * i + 0],  v0.x, s0);
      s0 = fmaf(xr[4 * i + 1],  v0.y, s0);
      s0 = fmaf(xr[4 * i + 2],  v0.z, s0);
      s0 = fmaf(xr[4 * i + 3],  v0.w, s0);
      s1 = fmaf(xr[4 * i + 4],  v1.x, s1);
      s1 = fmaf(xr[4 * i + 5],  v1.y, s1);
      s1 = fmaf(xr[4 * i + 6],  v1.z, s1);
      s1 = fmaf(xr[4 * i + 7],  v1.w, s1);
      s2 = fmaf(xr[4 * i + 8],  v2.x, s2);
      s2 = fmaf(xr[4 * i + 9],  v2.y, s2);
      s2 = fmaf(xr[4 * i + 10], v2.z, s2);
      s2 = fmaf(xr[4 * i + 11], v2.w, s2);
      s3 = fmaf(xr[4 * i + 12], v3.x, s3);
      s3 = fmaf(xr[4 * i + 13], v3.y, s3);
      s3 = fmaf(xr[4 * i + 14], v3.z, s3);
      s3 = fmaf(xr[4 * i + 15], v3.w, s3);
    }
    const float s = (s0 + s1) + (s2 + s3);
    if (s > best) { best = s; bidx = k; }  // strict > keeps earliest k (ref tie-break)
  }

  // Outputs: x_out[b][e][c] = E[bidx][e] (coalesced across lanes per e);
  // E gather is from the 256 KB L2-hot table.
  float* __restrict__ xo = xout + (size_t)b * (EMB * (size_t)CODES) + c;
  const float* __restrict__ Eb = E + bidx * EMB;
  #pragma unroll
  for (int e = 0; e < EMB; ++e) xo[(size_t)e * CODES] = Eb[e];

  iout[(size_t)b * CODES + c] = (float)bidx;
}

extern "C" void kernel_launch(void* const* d_in, const int* in_sizes, int n_in,
                              void* d_out, int out_size, void* d_ws, size_t ws_size,
                              hipStream_t stream) {
  const float* x = (const float*)d_in[0];  // [16, 64, 16384]
  const float* E = (const float*)d_in[1];  // [1024, 64]
  float* xout = (float*)d_out;                         // 16*64*16384 floats
  float* iout = (float*)d_out + (size_t)BB * EMB * CODES;  // 16*16384 floats

  dim3 grid(CODES / 256, BB);
  vq_kernel<<<grid, 256, 0, stream>>>(x, E, xout, iout);
}

// Round 2
// 243.056 us; speedup vs baseline: 3.2332x; 3.2332x over previous
//
#include <hip/hip_runtime.h>

// VQ codebook argmin via bf16x3-split MFMA GEMM + quantized top-2 + fp32 rescore.
//   x_in: [B=16, EMB=64, CODES=16384] f32 ; E: [1024, 64] f32
//   out0: x_out [B,EMB,CODES] f32 = E[argmin] ; out1: indices as f32
// score = dot(x, E_k) - 0.5*||E_k||^2  (argmax == argmin of dist2)

#define BB 16
#define EMB 64
#define CODES 16384
#define NT 1024
#define NTILES 64  // 1024 codes / 16 per MFMA n-tile

typedef __attribute__((ext_vector_type(8))) short s16x8;   // 8 bf16 (4 VGPRs)
typedef __attribute__((ext_vector_type(4))) float f32x4;   // MFMA acc
typedef __attribute__((ext_vector_type(4))) int i32x4;
typedef unsigned int u32;

__device__ inline short bf16_hi(float f) { return (short)(__builtin_bit_cast(u32, f) >> 16); }
__device__ inline float hi_part(float f) { return __builtin_bit_cast(float, __builtin_bit_cast(u32, f) & 0xFFFF0000u); }
__device__ inline u32 umin_(u32 a, u32 b) { return a < b ? a : b; }
__device__ inline u32 umax_(u32 a, u32 b) { return a > b ? a : b; }

// ---------- prologue: E -> bf16 hi/lo B-fragments in ws + h[n] = -0.5*||E_n||^2 ----------
// B-frag layout for mfma_f32_16x16x32_bf16: lane l holds B[k=(l>>4)*8+j][n=(l&15)].
// ws layout: per n-tile nt (4096 B): [hi ks0 | hi ks1 | lo ks0 | lo ks1] x (64 lanes * 16 B)
__global__ __launch_bounds__(256) void vq_prep(const float* __restrict__ E,
                                               char* __restrict__ wsE,
                                               float* __restrict__ wsh) {
  const int bid = blockIdx.x, tid = threadIdx.x;
  if (bid < 32) {
    const int gid = bid * 256 + tid;              // 8192 tasks: nt(64) x ks(2) x lane(64)
    const int nt = gid >> 7, ks = (gid >> 6) & 1, lane = gid & 63;
    const int col = lane & 15, quad = lane >> 4;
    const int n = nt * 16 + col;
    const int k0 = ks * 32 + quad * 8;
    const float* ep = E + n * EMB + k0;
    s16x8 hv, lv;
    #pragma unroll
    for (int j = 0; j < 8; ++j) {
      float v = ep[j];
      float hf = hi_part(v);
      hv[j] = bf16_hi(v);
      lv[j] = bf16_hi(v - hf);   // v - hf exact in fp32
    }
    char* base = wsE + ((size_t)nt << 12) + ((size_t)ks << 10) + lane * 16;
    *(i32x4*)(base)        = __builtin_bit_cast(i32x4, hv);
    *(i32x4*)(base + 2048) = __builtin_bit_cast(i32x4, lv);
  } else {
    const int n = (bid - 32) * 256 + tid;
    if (n < NT) {
      const float4* ep = (const float4*)(E + n * EMB);
      float s = 0.f;
      #pragma unroll
      for (int g = 0; g < 16; ++g) { float4 v = ep[g]; s += v.x*v.x + v.y*v.y + v.z*v.z + v.w*v.w; }
      wsh[n] = -0.5f * s;
    }
  }
}

// ---------- main: block = 256 queries of one b; wave = 4 m-tiles (64 queries) ----------
__global__ __launch_bounds__(256, 3) void vq_main(
    const float* __restrict__ x, const float* __restrict__ E,
    const char* __restrict__ wsE, const float* __restrict__ wsh,
    float* __restrict__ xout, float* __restrict__ iout) {
  __shared__ uint2 cand[256];
  const int tid = threadIdx.x;
  const int wave = tid >> 6, lane = tid & 63;
  const int col = lane & 15, quad = lane >> 4;
  const int b = blockIdx.y;
  const int c0 = blockIdx.x * 256;
  const int cw = c0 + wave * 64;

  // A fragments (queries): lane holds A[m=col][k=quad*8+j], k offset 32 per ks.
  // Loaded once per block from global (4x64B segments per instr), split hi/lo.
  s16x8 ah[4][2], al[4][2];
  #pragma unroll
  for (int mt = 0; mt < 4; ++mt) {
    #pragma unroll
    for (int ks = 0; ks < 2; ++ks) {
      s16x8 hv, lv;
      #pragma unroll
      for (int j = 0; j < 8; ++j) {
        const int e = ks * 32 + quad * 8 + j;
        float v = x[((size_t)b * EMB + e) * CODES + (size_t)(cw + mt * 16 + col)];
        float hf = hi_part(v);
        hv[j] = bf16_hi(v);
        lv[j] = bf16_hi(v - hf);
      }
      ah[mt][ks] = hv;
      al[mt][ks] = lv;
    }
  }

  // Running top-2 packed keys per (m-tile, acc-reg) slot.
  // key = (u32)((score + h + 96) * 2^14) << 10 | (1023 - n)
  //  - quant granularity 6.1e-5 (<< gaps of interest); index embedded => 3-op update
  //  - larger (1023-n) wins ties => earliest index, matching argmin first-occurrence
  u32 k1[4][4], k2[4][4];
  #pragma unroll
  for (int mt = 0; mt < 4; ++mt)
    #pragma unroll
    for (int r = 0; r < 4; ++r) { k1[mt][r] = 0u; k2[mt][r] = 0u; }

  u32 inv = 1023u - (u32)col;
  const char* p = wsE + lane * 16;
  const float* hp = wsh + col;

  for (int nt = 0; nt < NTILES; ++nt) {
    s16x8 bh0 = __builtin_bit_cast(s16x8, *(const i32x4*)(p));
    s16x8 bh1 = __builtin_bit_cast(s16x8, *(const i32x4*)(p + 1024));
    s16x8 bl0 = __builtin_bit_cast(s16x8, *(const i32x4*)(p + 2048));
    s16x8 bl1 = __builtin_bit_cast(s16x8, *(const i32x4*)(p + 3072));
    const float hl = *hp;                       // h for this lane's code col
    const float C = fmaf(hl, 16384.f, 96.f * 16384.f);

    f32x4 acc[4];
    #pragma unroll
    for (int mt = 0; mt < 4; ++mt) {
      acc[mt] = (f32x4){0.f, 0.f, 0.f, 0.f};
      acc[mt] = __builtin_amdgcn_mfma_f32_16x16x32_bf16(ah[mt][0], bh0, acc[mt], 0, 0, 0);
      acc[mt] = __builtin_amdgcn_mfma_f32_16x16x32_bf16(ah[mt][1], bh1, acc[mt], 0, 0, 0);
      acc[mt] = __builtin_amdgcn_mfma_f32_16x16x32_bf16(al[mt][0], bh0, acc[mt], 0, 0, 0);
      acc[mt] = __builtin_amdgcn_mfma_f32_16x16x32_bf16(al[mt][1], bh1, acc[mt], 0, 0, 0);
      acc[mt] = __builtin_amdgcn_mfma_f32_16x16x32_bf16(ah[mt][0], bl0, acc[mt], 0, 0, 0);
      acc[mt] = __builtin_amdgcn_mfma_f32_16x16x32_bf16(ah[mt][1], bl1, acc[mt], 0, 0, 0);
    }

    #pragma unroll
    for (int mt = 0; mt < 4; ++mt) {
      #pragma unroll
      for (int r = 0; r < 4; ++r) {
        u32 q = (u32)fmaf(acc[mt][r], 16384.f, C);   // always > 0 (|dot|<~45, +96 offset)
        u32 key = (q << 10) + inv;
        u32 t = umin_(key, k1[mt][r]);
        k1[mt][r] = umax_(key, k1[mt][r]);
        k2[mt][r] = umax_(t, k2[mt][r]);
      }
    }
    inv -= 16u;
    p += 4096;
    hp += 16;
  }

  // Merge top-2 across the 16 col-lanes (xor 1,2,4,8 stays inside the quad group).
  #pragma unroll
  for (int mt = 0; mt < 4; ++mt) {
    #pragma unroll
    for (int r = 0; r < 4; ++r) {
      u32 a1 = k1[mt][r], a2 = k2[mt][r];
      #pragma unroll
      for (int m = 1; m <= 8; m <<= 1) {
        u32 r1 = __shfl_xor(a1, m, 64);
        u32 r2 = __shfl_xor(a2, m, 64);
        u32 t = umin_(a1, r1);
        a1 = umax_(a1, r1);
        a2 = umax_(umax_(a2, r2), t);
      }
      // C/D layout: row = quad*4 + r  -> local query id
      if (col == r) cand[wave * 64 + mt * 16 + quad * 4 + r] = make_uint2(a1, a2);
    }
  }
  __syncthreads();

  // Epilogue: one thread per query. Exact fp32 rescore of the two candidates,
  // then gather winning E row and write outputs.
  const u32 K1 = cand[tid].x, K2 = cand[tid].y;
  const int i1 = 1023 - (int)(K1 & 1023u);
  const int i2 = 1023 - (int)(K2 & 1023u);
  const float* xq = x + (size_t)b * EMB * CODES + (size_t)(c0 + tid);
  const float4* e1 = (const float4*)(E + i1 * EMB);
  const float4* e2 = (const float4*)(E + i2 * EMB);
  float d10 = 0, d11 = 0, d12 = 0, d13 = 0, d20 = 0, d21 = 0, d22 = 0, d23 = 0;
  #pragma unroll
  for (int g = 0; g < 16; ++g) {
    float4 a = e1[g], c4 = e2[g];
    float x0 = xq[(size_t)(4 * g + 0) * CODES];
    float x1 = xq[(size_t)(4 * g + 1) * CODES];
    float x2 = xq[(size_t)(4 * g + 2) * CODES];
    float x3 = xq[(size_t)(4 * g + 3) * CODES];
    d10 = fmaf(x0, a.x, d10);  d11 = fmaf(x1, a.y, d11);
    d12 = fmaf(x2, a.z, d12);  d13 = fmaf(x3, a.w, d13);
    d20 = fmaf(x0, c4.x, d20); d21 = fmaf(x1, c4.y, d21);
    d22 = fmaf(x2, c4.z, d22); d23 = fmaf(x3, c4.w, d23);
  }
  const float s1 = ((d10 + d11) + (d12 + d13)) + wsh[i1];
  const float s2 = ((d20 + d21) + (d22 + d23)) + wsh[i2];
  const bool take2 = (s2 > s1) || (s2 == s1 && i2 < i1);
  const int idx = take2 ? i2 : i1;

  const float* Er = E + idx * EMB;
  float* xo = xout + (size_t)b * EMB * CODES + (size_t)(c0 + tid);
  #pragma unroll
  for (int e = 0; e < EMB; ++e) xo[(size_t)e * CODES] = Er[e];
  iout[(size_t)b * CODES + (size_t)(c0 + tid)] = (float)idx;
}

extern "C" void kernel_launch(void* const* d_in, const int* in_sizes, int n_in,
                              void* d_out, int out_size, void* d_ws, size_t ws_size,
                              hipStream_t stream) {
  const float* x = (const float*)d_in[0];   // [16, 64, 16384]
  const float* E = (const float*)d_in[1];   // [1024, 64]
  float* xout = (float*)d_out;
  float* iout = (float*)d_out + (size_t)BB * EMB * CODES;

  char* wsE = (char*)d_ws;                         // 256 KB fragment table
  float* wsh = (float*)((char*)d_ws + (256 << 10)); // 4 KB h table

  vq_prep<<<36, 256, 0, stream>>>(E, wsE, wsh);
  vq_main<<<dim3(CODES / 256, BB), 256, 0, stream>>>(x, E, wsE, wsh, xout, iout);
}

// Round 3
// 225.819 us; speedup vs baseline: 3.4799x; 1.0763x over previous
//
#include <hip/hip_runtime.h>

// VQ codebook argmin via bf16x3-split MFMA GEMM + quantized top-2 + fp32 rescore.
//   x_in: [B=16, EMB=64, CODES=16384] f32 ; E: [1024, 64] f32
//   out0: x_out [B,EMB,CODES] f32 = E[argmin] ; out1: indices as f32
// score = dot(x, E_k) - 0.5*||E_k||^2  (argmax == argmin of dist2)
// Scan computes 16384*(score+128) in the MFMA accumulator directly:
//   A = x * 2^14 (exact), C-init = wsh2[n] = 16384*(h[n]+128).

#define BB 16
#define EMB 64
#define CODES 16384
#define NT 1024
#define NTILES 64

typedef __attribute__((ext_vector_type(8))) short s16x8;   // 8 bf16 (4 VGPRs)
typedef __attribute__((ext_vector_type(4))) float f32x4;   // MFMA acc
typedef __attribute__((ext_vector_type(4))) int i32x4;
typedef unsigned int u32;

__device__ inline short bf16_hi(float f) { return (short)(__builtin_bit_cast(u32, f) >> 16); }
__device__ inline float hi_part(float f) { return __builtin_bit_cast(float, __builtin_bit_cast(u32, f) & 0xFFFF0000u); }
__device__ inline u32 umin_(u32 a, u32 b) { return a < b ? a : b; }
__device__ inline u32 umax_(u32 a, u32 b) { return a > b ? a : b; }

// ws layout:
//   [0, 256K+4K)        : B-fragment table (64 n-tiles x 4096 B) + 4K over-read pad
//   [266240, +4K)       : wsh  = -0.5*||E_n||^2            (epilogue rescore)
//   [270336, +4K+64)    : wsh2 = 16384*(wsh[n]+128) + pad  (scan C-init)
#define WSE_OFF   0
#define WSH_OFF   266240
#define WSH2_OFF  270336

__global__ __launch_bounds__(256) void vq_prep(const float* __restrict__ E,
                                               char* __restrict__ wsE,
                                               float* __restrict__ wsh,
                                               float* __restrict__ wsh2) {
  const int bid = blockIdx.x, tid = threadIdx.x;
  if (bid < 32) {
    const int gid = bid * 256 + tid;              // 8192 tasks: nt(64) x ks(2) x lane(64)
    const int nt = gid >> 7, ks = (gid >> 6) & 1, lane = gid & 63;
    const int col = lane & 15, quad = lane >> 4;
    const int n = nt * 16 + col;
    const int k0 = ks * 32 + quad * 8;
    const float* ep = E + n * EMB + k0;
    s16x8 hv, lv;
    #pragma unroll
    for (int j = 0; j < 8; ++j) {
      float v = ep[j];
      float hf = hi_part(v);
      hv[j] = bf16_hi(v);
      lv[j] = bf16_hi(v - hf);   // v - hf exact in fp32
    }
    char* base = wsE + ((size_t)nt << 12) + ((size_t)ks << 10) + lane * 16;
    *(i32x4*)(base)        = __builtin_bit_cast(i32x4, hv);
    *(i32x4*)(base + 2048) = __builtin_bit_cast(i32x4, lv);
  } else {
    const int n = (bid - 32) * 256 + tid;
    if (n < NT) {
      const float4* ep = (const float4*)(E + n * EMB);
      float s = 0.f;
      #pragma unroll
      for (int g = 0; g < 16; ++g) { float4 v = ep[g]; s += v.x*v.x + v.y*v.y + v.z*v.z + v.w*v.w; }
      const float h = -0.5f * s;
      wsh[n] = h;
      wsh2[n] = 16384.f * (h + 128.f);
    }
  }
}

// One wave per block; 64 queries (4 m-tiles) per wave; 4096 blocks.
__global__ __launch_bounds__(64, 2) void vq_main(
    const float* __restrict__ x, const float* __restrict__ E,
    const char* __restrict__ wsE, const float* __restrict__ wsh,
    const float* __restrict__ wsh2,
    float* __restrict__ xout, float* __restrict__ iout) {
  __shared__ uint2 cand[64];
  const int lane = threadIdx.x;
  const int col = lane & 15, quad = lane >> 4;
  const int b = blockIdx.y;
  const int c0 = blockIdx.x * 64;

  // A fragments: lane holds A[m=col][k=quad*8+j] per (mt, ks); query scaled by 2^14.
  s16x8 ah[4][2], al[4][2];
  #pragma unroll
  for (int mt = 0; mt < 4; ++mt) {
    #pragma unroll
    for (int ks = 0; ks < 2; ++ks) {
      s16x8 hv, lv;
      #pragma unroll
      for (int j = 0; j < 8; ++j) {
        const int e = ks * 32 + quad * 8 + j;
        float v = x[((size_t)b * EMB + e) * CODES + (size_t)(c0 + mt * 16 + col)] * 16384.f;
        float hf = hi_part(v);
        hv[j] = bf16_hi(v);
        lv[j] = bf16_hi(v - hf);
      }
      ah[mt][ks] = hv;
      al[mt][ks] = lv;
    }
  }

  // Running top-2 packed keys per (m-tile, acc-reg) = per query (per this lane's col).
  // key = (u32)acc << 10 | (1023 - n); acc = 16384*(score+128) > 0, < 2^22.
  // Larger (1023-n) wins ties => earliest index (np.argmin first-occurrence).
  u32 k1[4][4], k2[4][4];
  #pragma unroll
  for (int mt = 0; mt < 4; ++mt)
    #pragma unroll
    for (int r = 0; r < 4; ++r) { k1[mt][r] = 0u; k2[mt][r] = 0u; }

  u32 inv = 1023u - (u32)col;
  const char* p = wsE + lane * 16;
  const float* hp = wsh2 + col;

  // Software pipeline: B frags + C-init for nt+1 prefetched while scoring nt.
  i32x4 nb0 = *(const i32x4*)(p);
  i32x4 nb1 = *(const i32x4*)(p + 1024);
  i32x4 nb2 = *(const i32x4*)(p + 2048);
  i32x4 nb3 = *(const i32x4*)(p + 3072);
  float nch = *hp;

  #pragma unroll 4
  for (int nt = 0; nt < NTILES; ++nt) {
    const s16x8 bh0 = __builtin_bit_cast(s16x8, nb0);
    const s16x8 bh1 = __builtin_bit_cast(s16x8, nb1);
    const s16x8 bl0 = __builtin_bit_cast(s16x8, nb2);
    const s16x8 bl1 = __builtin_bit_cast(s16x8, nb3);
    const float ch = nch;

    p += 4096; hp += 16;                  // last iter over-reads into ws pad (unused)
    nb0 = *(const i32x4*)(p);
    nb1 = *(const i32x4*)(p + 1024);
    nb2 = *(const i32x4*)(p + 2048);
    nb3 = *(const i32x4*)(p + 3072);
    nch = *hp;

    f32x4 acc[4];
    #pragma unroll
    for (int mt = 0; mt < 4; ++mt) {
      acc[mt] = (f32x4){ch, ch, ch, ch};  // quantizer offset folded into C
      acc[mt] = __builtin_amdgcn_mfma_f32_16x16x32_bf16(ah[mt][0], bh0, acc[mt], 0, 0, 0);
      acc[mt] = __builtin_amdgcn_mfma_f32_16x16x32_bf16(ah[mt][1], bh1, acc[mt], 0, 0, 0);
      acc[mt] = __builtin_amdgcn_mfma_f32_16x16x32_bf16(al[mt][0], bh0, acc[mt], 0, 0, 0);
      acc[mt] = __builtin_amdgcn_mfma_f32_16x16x32_bf16(al[mt][1], bh1, acc[mt], 0, 0, 0);
      acc[mt] = __builtin_amdgcn_mfma_f32_16x16x32_bf16(ah[mt][0], bl0, acc[mt], 0, 0, 0);
      acc[mt] = __builtin_amdgcn_mfma_f32_16x16x32_bf16(ah[mt][1], bl1, acc[mt], 0, 0, 0);
    }

    #pragma unroll
    for (int mt = 0; mt < 4; ++mt) {
      #pragma unroll
      for (int r = 0; r < 4; ++r) {
        u32 q = (u32)acc[mt][r];              // v_cvt_u32_f32 (trunc), always >= 0
        u32 key = (q << 10) + inv;
        u32 t = umin_(key, k1[mt][r]);
        k1[mt][r] = umax_(key, k1[mt][r]);
        k2[mt][r] = umax_(t, k2[mt][r]);
      }
    }
    inv -= 16u;
  }

  // Merge top-2 across the 16 col-lanes (xor 1,2,4,8 stays inside the quad group).
  #pragma unroll
  for (int mt = 0; mt < 4; ++mt) {
    #pragma unroll
    for (int r = 0; r < 4; ++r) {
      u32 a1 = k1[mt][r], a2 = k2[mt][r];
      #pragma unroll
      for (int m = 1; m <= 8; m <<= 1) {
        u32 r1 = __shfl_xor(a1, m, 64);
        u32 r2 = __shfl_xor(a2, m, 64);
        u32 t = umin_(a1, r1);
        a1 = umax_(a1, r1);
        a2 = umax_(umax_(a2, r2), t);
      }
      // C/D layout: local query = mt*16 + quad*4 + r
      if (col == r) cand[mt * 16 + quad * 4 + r] = make_uint2(a1, a2);
    }
  }
  __syncthreads();

  // Epilogue: lane q rescores its query's two candidates in exact fp32.
  const u32 K1 = cand[lane].x, K2 = cand[lane].y;
  const int i1 = 1023 - (int)(K1 & 1023u);
  const int i2 = 1023 - (int)(K2 & 1023u);
  const float* xq = x + (size_t)b * EMB * CODES + (size_t)(c0 + lane);
  const float4* e1 = (const float4*)(E + i1 * EMB);
  const float4* e2 = (const float4*)(E + i2 * EMB);
  float d10 = 0, d11 = 0, d12 = 0, d13 = 0, d20 = 0, d21 = 0, d22 = 0, d23 = 0;
  #pragma unroll
  for (int g = 0; g < 16; ++g) {
    float4 a = e1[g], c4 = e2[g];
    float x0 = xq[(size_t)(4 * g + 0) * CODES];
    float x1 = xq[(size_t)(4 * g + 1) * CODES];
    float x2 = xq[(size_t)(4 * g + 2) * CODES];
    float x3 = xq[(size_t)(4 * g + 3) * CODES];
    d10 = fmaf(x0, a.x, d10);  d11 = fmaf(x1, a.y, d11);
    d12 = fmaf(x2, a.z, d12);  d13 = fmaf(x3, a.w, d13);
    d20 = fmaf(x0, c4.x, d20); d21 = fmaf(x1, c4.y, d21);
    d22 = fmaf(x2, c4.z, d22); d23 = fmaf(x3, c4.w, d23);
  }
  const float s1 = ((d10 + d11) + (d12 + d13)) + wsh[i1];
  const float s2 = ((d20 + d21) + (d22 + d23)) + wsh[i2];
  const bool take2 = (s2 > s1) || (s2 == s1 && i2 < i1);
  const int idx = take2 ? i2 : i1;

  const float* Er = E + idx * EMB;
  float* xo = xout + (size_t)b * EMB * CODES + (size_t)(c0 + lane);
  #pragma unroll
  for (int e = 0; e < EMB; ++e) xo[(size_t)e * CODES] = Er[e];
  iout[(size_t)b * CODES + (size_t)(c0 + lane)] = (float)idx;
}

extern "C" void kernel_launch(void* const* d_in, const int* in_sizes, int n_in,
                              void* d_out, int out_size, void* d_ws, size_t ws_size,
                              hipStream_t stream) {
  const float* x = (const float*)d_in[0];   // [16, 64, 16384]
  const float* E = (const float*)d_in[1];   // [1024, 64]
  float* xout = (float*)d_out;
  float* iout = (float*)d_out + (size_t)BB * EMB * CODES;

  char* wsE  = (char*)d_ws + WSE_OFF;
  float* wsh  = (float*)((char*)d_ws + WSH_OFF);
  float* wsh2 = (float*)((char*)d_ws + WSH2_OFF);

  vq_prep<<<36, 256, 0, stream>>>(E, wsE, wsh, wsh2);
  vq_main<<<dim3(CODES / 64, BB), 64, 0, stream>>>(x, E, wsE, wsh, wsh2, xout, iout);
}